// Round 1
// baseline (130.316 us; speedup 1.0000x reference)
//
#include <hip/hip_runtime.h>

#define Bn  4
#define TEn 512
#define TDn 256
#define HEn 128
#define HDn 256

__device__ __forceinline__ float tanh_fast(float x) {
    // tanh(x) = 1 - 2/(exp(2x)+1); exact at +/-inf (rcp(inf)=0, exp(-inf)=0)
    float e = __expf(2.0f * x);
    return 1.0f - 2.0f * __builtin_amdgcn_rcpf(e + 1.0f);
}

// Ws[r, c] = sum_k enc[r, k] * W[k, c],  r in [0, B*TE)
__global__ __launch_bounds__(512) void ws_gemm_kernel(
    const float* __restrict__ enc, const float* __restrict__ W,
    float* __restrict__ Ws)
{
    const int c  = threadIdx.x & (HEn - 1);
    const int rl = threadIdx.x >> 7;       // 4 rows per block
    const int r  = blockIdx.x * 4 + rl;
    const float* er = enc + r * HEn;       // wave-uniform -> scalar loads
    const float* wc = W + c;               // coalesced across lanes
    float acc = 0.f;
    #pragma unroll 8
    for (int k = 0; k < HEn; ++k)
        acc = fmaf(er[k], wc[k * HEn], acc);
    Ws[r * HEn + c] = acc;
}

__global__ __launch_bounds__(512) void attn_kernel(
    const float* __restrict__ enc, const float* __restrict__ dec,
    const float* __restrict__ U, const float* __restrict__ V,
    const float* __restrict__ Ws, float* __restrict__ c_out,
    float* __restrict__ e_out)
{
    const int bt   = blockIdx.x;      // b*TD + t
    const int b    = bt >> 8;         // TD = 256
    const int tid  = threadIdx.x;
    const int lane = tid & 63;
    const int wave = tid >> 6;        // 0..7

    __shared__ float uh[HEn];
    __shared__ float part[4][HEn];
    __shared__ float sc[TEn];
    __shared__ float redm[8];
    __shared__ float reds[8];

    // ---- Uh[f] = sum_k dec[bt, k] * U[k, f]  (4 k-partitions x 128 f)
    {
        const int f = tid & 127;
        const int p = tid >> 7;
        const float* d = dec + bt * HDn + p * 64;   // wave-uniform
        const float* u = U + (p * 64) * HEn + f;    // coalesced
        float acc = 0.f;
        #pragma unroll 8
        for (int k = 0; k < 64; ++k)
            acc = fmaf(d[k], u[k * HEn], acc);
        part[p][f] = acc;
    }
    __syncthreads();
    if (tid < HEn)
        uh[tid] = part[0][tid] + part[1][tid] + part[2][tid] + part[3][tid];
    __syncthreads();

    // ---- scores: sc[s] = sum_f V[f] * tanh(Ws[b,s,f] + uh[f]); wave per s
    {
        const float2 v2 = *(const float2*)(V  + 2 * lane);
        const float2 u2 = *(const float2*)(uh + 2 * lane);
        const float* wsb = Ws + (b * TEn) * HEn;
        #pragma unroll 2
        for (int i = 0; i < 64; ++i) {
            const int s = wave * 64 + i;
            const float2 w2 = *(const float2*)(wsb + s * HEn + 2 * lane);
            float x = tanh_fast(w2.x + u2.x) * v2.x
                    + tanh_fast(w2.y + u2.y) * v2.y;
            #pragma unroll
            for (int off = 32; off; off >>= 1)
                x += __shfl_xor(x, off, 64);
            if (lane == 0) sc[s] = x;
        }
    }
    __syncthreads();

    // ---- softmax over sc[0..511]; thread tid owns sc[tid]
    const float val = sc[tid];
    float m = val;
    #pragma unroll
    for (int off = 32; off; off >>= 1)
        m = fmaxf(m, __shfl_xor(m, off, 64));
    if (lane == 0) redm[wave] = m;
    __syncthreads();
    float bm = redm[0];
    #pragma unroll
    for (int w = 1; w < 8; ++w) bm = fmaxf(bm, redm[w]);
    const float ex = __expf(val - bm);
    float sm = ex;
    #pragma unroll
    for (int off = 32; off; off >>= 1)
        sm += __shfl_xor(sm, off, 64);
    if (lane == 0) reds[wave] = sm;
    __syncthreads();
    float bs = reds[0];
    #pragma unroll
    for (int w = 1; w < 8; ++w) bs += reds[w];
    const float e = ex * __builtin_amdgcn_rcpf(bs);
    e_out[bt * TEn + tid] = e;
    sc[tid] = e;                 // safe: all reads of old sc done before last sync
    __syncthreads();

    // ---- context: c[bt, h] = sum_s e[s] * enc[b, s, h]
    {
        const int h = tid & 127;
        const int p = tid >> 7;
        const float* eb = enc + (b * TEn + p * 128) * HEn + h;  // coalesced
        const float* ep = sc + p * 128;                         // LDS broadcast
        float acc = 0.f;
        #pragma unroll 4
        for (int i = 0; i < 128; ++i)
            acc = fmaf(ep[i], eb[i * HEn], acc);
        part[p][h] = acc;
    }
    __syncthreads();
    if (tid < HEn)
        c_out[bt * HEn + tid] = part[0][tid] + part[1][tid]
                              + part[2][tid] + part[3][tid];
}

extern "C" void kernel_launch(void* const* d_in, const int* in_sizes, int n_in,
                              void* d_out, int out_size, void* d_ws, size_t ws_size,
                              hipStream_t stream) {
    const float* enc = (const float*)d_in[0];   // [B,TE,HE]
    const float* dec = (const float*)d_in[1];   // [B,TD,HD]
    const float* W   = (const float*)d_in[2];   // [HE,HE]
    const float* U   = (const float*)d_in[3];   // [HD,HE]
    const float* V   = (const float*)d_in[4];   // [HE,1]
    float* out   = (float*)d_out;
    float* c_out = out;                         // [B,TD,HE]
    float* e_out = out + Bn * TDn * HEn;        // [B,TD,TE]
    float* Ws    = (float*)d_ws;                // [B,TE,HE] scratch, 1 MB

    ws_gemm_kernel<<<(Bn * TEn) / 4, 512, 0, stream>>>(enc, W, Ws);
    attn_kernel<<<Bn * TDn, 512, 0, stream>>>(enc, dec, U, V, Ws, c_out, e_out);
}

// Round 2
// 111.163 us; speedup vs baseline: 1.1723x; 1.1723x over previous
//
#include <hip/hip_runtime.h>

#define Bn  4
#define TEn 512
#define TDn 256
#define HEn 128
#define HDn 256

__device__ __forceinline__ float tanh_fast(float x) {
    // tanh(x) = 1 - 2/(exp(2x)+1); exact at +/-inf (rcp(inf)=0, exp(-inf)=0)
    float e = __expf(2.0f * x);
    return 1.0f - 2.0f * __builtin_amdgcn_rcpf(e + 1.0f);
}

// Ws[r, c] = sum_k enc[r, k] * W[k, c]; 4 rows per block, enc rows staged in LDS.
__global__ __launch_bounds__(512) void ws_gemm_kernel(
    const float* __restrict__ enc, const float* __restrict__ W,
    float* __restrict__ Ws)
{
    __shared__ __align__(16) float enc_lds[4 * HEn];
    const int tid = threadIdx.x;
    const int c   = tid & (HEn - 1);
    const int rl  = tid >> 7;              // wave-uniform (2 waves per row)
    const int r0  = blockIdx.x * 4;
    enc_lds[tid] = enc[r0 * HEn + tid];    // coalesced 2 KB stage
    __syncthreads();
    const float* wc = W + c;               // coalesced across lanes
    const float* er = enc_lds + rl * HEn;  // LDS broadcast
    float acc = 0.f;
    #pragma unroll 4
    for (int k = 0; k < HEn; k += 8) {
        float4 e0 = *(const float4*)(er + k);
        float4 e1 = *(const float4*)(er + k + 4);
        acc = fmaf(e0.x, wc[(k + 0) * HEn], acc);
        acc = fmaf(e0.y, wc[(k + 1) * HEn], acc);
        acc = fmaf(e0.z, wc[(k + 2) * HEn], acc);
        acc = fmaf(e0.w, wc[(k + 3) * HEn], acc);
        acc = fmaf(e1.x, wc[(k + 4) * HEn], acc);
        acc = fmaf(e1.y, wc[(k + 5) * HEn], acc);
        acc = fmaf(e1.z, wc[(k + 6) * HEn], acc);
        acc = fmaf(e1.w, wc[(k + 7) * HEn], acc);
    }
    Ws[(r0 + rl) * HEn + c] = acc;
}

__global__ __launch_bounds__(512) void attn_kernel(
    const float* __restrict__ enc, const float* __restrict__ dec,
    const float* __restrict__ U, const float* __restrict__ V,
    const float* __restrict__ Ws, float* __restrict__ c_out,
    float* __restrict__ e_out)
{
    const int bt   = blockIdx.x;      // b*TD + t
    const int b    = bt >> 8;         // TD = 256
    const int tid  = threadIdx.x;
    const int lane = tid & 63;
    const int wave = tid >> 6;        // 0..7

    __shared__ __align__(16) float uh[HEn];
    __shared__ __align__(16) float part[16][HEn];   // 8 KB: uh partials + context partials
    __shared__ __align__(16) float sc[TEn];
    __shared__ __align__(16) float dec_lds[HDn];
    __shared__ float redm[8];
    __shared__ float reds[8];

    // ---- stage decoder row (1 KB, coalesced)
    if (tid < HDn) dec_lds[tid] = dec[bt * HDn + tid];
    __syncthreads();

    // ---- Uh[f] = sum_k dec[bt,k] * U[k,f]  (4 k-partitions x 128 f)
    {
        const int f = tid & 127;
        const int p = tid >> 7;                  // wave-uniform
        const float* d = dec_lds + p * 64;       // LDS broadcast
        const float* u = U + (p * 64) * HEn + f; // coalesced
        float acc = 0.f;
        #pragma unroll 8
        for (int k = 0; k < 64; ++k)
            acc = fmaf(d[k], u[k * HEn], acc);
        part[p][f] = acc;
    }
    __syncthreads();
    if (tid < HEn)
        uh[tid] = part[0][tid] + part[1][tid] + part[2][tid] + part[3][tid];
    __syncthreads();

    // ---- scores: lane = (s_sub = lane&7) x (f_grp = lane>>3, 16 f each)
    {
        const int s_sub = lane & 7;
        const int f0    = (lane >> 3) * 16;
        float4 vv[4], uu[4];
        #pragma unroll
        for (int j = 0; j < 4; ++j) {
            vv[j] = *(const float4*)(V  + f0 + 4 * j);
            uu[j] = *(const float4*)(uh + f0 + 4 * j);
        }
        const float* wsb = Ws + (b * TEn + wave * 64) * HEn;
        #pragma unroll 2
        for (int ci = 0; ci < 8; ++ci) {
            const float* wp = wsb + (ci * 8 + s_sub) * HEn + f0;
            float x = 0.f;
            #pragma unroll
            for (int j = 0; j < 4; ++j) {
                float4 w = ((const float4*)wp)[j];
                x = fmaf(vv[j].x, tanh_fast(w.x + uu[j].x), x);
                x = fmaf(vv[j].y, tanh_fast(w.y + uu[j].y), x);
                x = fmaf(vv[j].z, tanh_fast(w.z + uu[j].z), x);
                x = fmaf(vv[j].w, tanh_fast(w.w + uu[j].w), x);
            }
            // reduce across the 8 f-groups (lanes sharing s_sub)
            x += __shfl_xor(x, 8, 64);
            x += __shfl_xor(x, 16, 64);
            x += __shfl_xor(x, 32, 64);
            if (lane < 8) sc[wave * 64 + ci * 8 + lane] = x;
        }
    }
    __syncthreads();

    // ---- softmax over sc[0..511]; thread tid owns sc[tid]
    const float val = sc[tid];
    float m = val;
    #pragma unroll
    for (int off = 32; off; off >>= 1)
        m = fmaxf(m, __shfl_xor(m, off, 64));
    if (lane == 0) redm[wave] = m;
    __syncthreads();
    float bm = redm[0];
    #pragma unroll
    for (int w = 1; w < 8; ++w) bm = fmaxf(bm, redm[w]);
    const float ex = __expf(val - bm);
    float sm = ex;
    #pragma unroll
    for (int off = 32; off; off >>= 1)
        sm += __shfl_xor(sm, off, 64);
    if (lane == 0) reds[wave] = sm;
    __syncthreads();
    float bs = reds[0];
    #pragma unroll
    for (int w = 1; w < 8; ++w) bs += reds[w];
    const float e = ex * __builtin_amdgcn_rcpf(bs);
    e_out[bt * TEn + tid] = e;
    sc[tid] = e;                 // all reads of old sc complete before last sync
    __syncthreads();

    // ---- context: c[bt, h] = sum_s e[s] * enc[b, s, h]
    // thread = (hl = tid&31 -> h = 4*hl..4*hl+3) x (sp = tid>>5, 32 s each)
    {
        const int hl = tid & 31;
        const int sp = tid >> 5;
        const float* eb = enc + (b * TEn + sp * 32) * HEn + hl * 4;
        const float* ep = sc + sp * 32;
        float4 a4 = {0.f, 0.f, 0.f, 0.f};
        #pragma unroll 4
        for (int i = 0; i < 32; ++i) {
            const float ei = ep[i];                       // LDS broadcast
            const float4 ev = *(const float4*)(eb + i * HEn);  // coalesced
            a4.x = fmaf(ei, ev.x, a4.x);
            a4.y = fmaf(ei, ev.y, a4.y);
            a4.z = fmaf(ei, ev.z, a4.z);
            a4.w = fmaf(ei, ev.w, a4.w);
        }
        *(float4*)&part[sp][hl * 4] = a4;
    }
    __syncthreads();
    if (tid < HEn) {
        float s = 0.f;
        #pragma unroll
        for (int p = 0; p < 16; ++p) s += part[p][tid];
        c_out[bt * HEn + tid] = s;
    }
}

extern "C" void kernel_launch(void* const* d_in, const int* in_sizes, int n_in,
                              void* d_out, int out_size, void* d_ws, size_t ws_size,
                              hipStream_t stream) {
    const float* enc = (const float*)d_in[0];   // [B,TE,HE]
    const float* dec = (const float*)d_in[1];   // [B,TD,HD]
    const float* W   = (const float*)d_in[2];   // [HE,HE]
    const float* U   = (const float*)d_in[3];   // [HD,HE]
    const float* V   = (const float*)d_in[4];   // [HE,1]
    float* out   = (float*)d_out;
    float* c_out = out;                         // [B,TD,HE]
    float* e_out = out + Bn * TDn * HEn;        // [B,TD,TE]
    float* Ws    = (float*)d_ws;                // [B,TE,HE] scratch, 1 MB

    ws_gemm_kernel<<<(Bn * TEn) / 4, 512, 0, stream>>>(enc, W, Ws);
    attn_kernel<<<Bn * TDn, 512, 0, stream>>>(enc, dec, U, V, Ws, c_out, e_out);
}

// Round 3
// 95.991 us; speedup vs baseline: 1.3576x; 1.1580x over previous
//
#include <hip/hip_runtime.h>

#define Bn  4
#define TEn 512
#define TDn 256
#define HEn 128
#define HDn 256

__device__ __forceinline__ float tanh_fast(float x) {
    // tanh(x) = 1 - 2/(exp(2x)+1); exact at +/-inf (rcp(inf)=0, exp(-inf)=0)
    float e = __expf(2.0f * x);
    return 1.0f - 2.0f * __builtin_amdgcn_rcpf(e + 1.0f);
}

// Ws[r, c] = sum_k enc[r, k] * W[k, c]; 4 rows per block, enc rows staged in LDS.
__global__ __launch_bounds__(512) void ws_gemm_kernel(
    const float* __restrict__ enc, const float* __restrict__ W,
    float* __restrict__ Ws)
{
    __shared__ __align__(16) float enc_lds[4 * HEn];
    const int tid = threadIdx.x;
    const int c   = tid & (HEn - 1);
    const int rl  = tid >> 7;              // wave-uniform
    const int r0  = blockIdx.x * 4;
    enc_lds[tid] = enc[r0 * HEn + tid];    // coalesced 2 KB stage
    __syncthreads();
    const float* wc = W + c;               // coalesced across lanes
    const float* er = enc_lds + rl * HEn;  // LDS broadcast
    float acc = 0.f;
    #pragma unroll 4
    for (int k = 0; k < HEn; k += 8) {
        float4 e0 = *(const float4*)(er + k);
        float4 e1 = *(const float4*)(er + k + 4);
        acc = fmaf(e0.x, wc[(k + 0) * HEn], acc);
        acc = fmaf(e0.y, wc[(k + 1) * HEn], acc);
        acc = fmaf(e0.z, wc[(k + 2) * HEn], acc);
        acc = fmaf(e0.w, wc[(k + 3) * HEn], acc);
        acc = fmaf(e1.x, wc[(k + 4) * HEn], acc);
        acc = fmaf(e1.y, wc[(k + 5) * HEn], acc);
        acc = fmaf(e1.z, wc[(k + 6) * HEn], acc);
        acc = fmaf(e1.w, wc[(k + 7) * HEn], acc);
    }
    Ws[(r0 + rl) * HEn + c] = acc;
}

// One block per (b, t-pair): amortizes Ws/enc reads over 2 decoder steps,
// and gives each wave 2 independent dependency chains.
__global__ __launch_bounds__(512, 4) void attn_kernel(
    const float* __restrict__ enc, const float* __restrict__ dec,
    const float* __restrict__ U, const float* __restrict__ V,
    const float* __restrict__ Ws, float* __restrict__ c_out,
    float* __restrict__ e_out)
{
    const int bp   = blockIdx.x;        // b*128 + tq
    const int b    = bp >> 7;
    const int t0   = (bp & 127) * 2;
    const int bt0  = b * TDn + t0;      // rows bt0, bt0+1
    const int tid  = threadIdx.x;
    const int lane = tid & 63;
    const int wave = tid >> 6;          // 0..7

    __shared__ __align__(16) float dec_lds[2 * HDn];   // 2 KB
    __shared__ __align__(16) float uh0[HEn];           // 0.5 KB
    __shared__ __align__(16) float uh1[HEn];           // 0.5 KB
    __shared__ __align__(16) float part[32][HEn];      // 16 KB
    __shared__ __align__(16) float sc0[TEn];           // 2 KB
    __shared__ __align__(16) float sc1[TEn];           // 2 KB
    __shared__ float redm[2][8];
    __shared__ float reds[2][8];

    // ---- stage both decoder rows (contiguous, coalesced 2 KB)
    dec_lds[tid] = dec[bt0 * HDn + tid];
    __syncthreads();

    // ---- Uh[t][f] = sum_k dec[bt0+t, k] * U[k, f]   (4 k-partitions x 128 f)
    {
        const int f = tid & 127;
        const int p = tid >> 7;                        // wave-uniform
        const float* d0 = dec_lds + p * 64;            // LDS broadcast
        const float* d1 = dec_lds + HDn + p * 64;
        const float* u  = U + (p * 64) * HEn + f;      // coalesced
        float a0 = 0.f, a1 = 0.f;
        #pragma unroll 8
        for (int k = 0; k < 64; ++k) {
            const float uk = u[k * HEn];               // loaded once, used twice
            a0 = fmaf(d0[k], uk, a0);
            a1 = fmaf(d1[k], uk, a1);
        }
        part[p][f]     = a0;
        part[4 + p][f] = a1;
    }
    __syncthreads();
    if (tid < HEn)
        uh0[tid] = part[0][tid] + part[1][tid] + part[2][tid] + part[3][tid];
    else if (tid < 2 * HEn) {
        const int f = tid - HEn;
        uh1[f] = part[4][f] + part[5][f] + part[6][f] + part[7][f];
    }
    __syncthreads();

    // ---- scores for both t: lane = (s_sub = lane&7) x (f_grp = lane>>3, 16 f)
    {
        const int s_sub = lane & 7;
        const int f0    = (lane >> 3) * 16;
        float4 vv[4], u0[4], u1[4];
        #pragma unroll
        for (int j = 0; j < 4; ++j) {
            vv[j] = *(const float4*)(V   + f0 + 4 * j);
            u0[j] = *(const float4*)(uh0 + f0 + 4 * j);
            u1[j] = *(const float4*)(uh1 + f0 + 4 * j);
        }
        const float* wsb = Ws + (b * TEn + wave * 64) * HEn;
        #pragma unroll 2
        for (int ci = 0; ci < 8; ++ci) {
            const float* wp = wsb + (ci * 8 + s_sub) * HEn + f0;
            float x0 = 0.f, x1 = 0.f;
            #pragma unroll
            for (int j = 0; j < 4; ++j) {
                float4 w = ((const float4*)wp)[j];     // one load, two chains
                x0 = fmaf(vv[j].x, tanh_fast(w.x + u0[j].x), x0);
                x1 = fmaf(vv[j].x, tanh_fast(w.x + u1[j].x), x1);
                x0 = fmaf(vv[j].y, tanh_fast(w.y + u0[j].y), x0);
                x1 = fmaf(vv[j].y, tanh_fast(w.y + u1[j].y), x1);
                x0 = fmaf(vv[j].z, tanh_fast(w.z + u0[j].z), x0);
                x1 = fmaf(vv[j].z, tanh_fast(w.z + u1[j].z), x1);
                x0 = fmaf(vv[j].w, tanh_fast(w.w + u0[j].w), x0);
                x1 = fmaf(vv[j].w, tanh_fast(w.w + u1[j].w), x1);
            }
            x0 += __shfl_xor(x0, 8, 64);
            x1 += __shfl_xor(x1, 8, 64);
            x0 += __shfl_xor(x0, 16, 64);
            x1 += __shfl_xor(x1, 16, 64);
            x0 += __shfl_xor(x0, 32, 64);
            x1 += __shfl_xor(x1, 32, 64);
            if (lane < 8) {
                sc0[wave * 64 + ci * 8 + lane] = x0;
                sc1[wave * 64 + ci * 8 + lane] = x1;
            }
        }
    }
    __syncthreads();

    // ---- softmax over both score rows; thread tid owns s = tid
    const float v0 = sc0[tid];
    const float v1 = sc1[tid];
    float m0 = v0, m1 = v1;
    #pragma unroll
    for (int off = 32; off; off >>= 1) {
        m0 = fmaxf(m0, __shfl_xor(m0, off, 64));
        m1 = fmaxf(m1, __shfl_xor(m1, off, 64));
    }
    if (lane == 0) { redm[0][wave] = m0; redm[1][wave] = m1; }
    __syncthreads();
    float bm0 = redm[0][0], bm1 = redm[1][0];
    #pragma unroll
    for (int w = 1; w < 8; ++w) {
        bm0 = fmaxf(bm0, redm[0][w]);
        bm1 = fmaxf(bm1, redm[1][w]);
    }
    const float ex0 = __expf(v0 - bm0);
    const float ex1 = __expf(v1 - bm1);
    float s0 = ex0, s1 = ex1;
    #pragma unroll
    for (int off = 32; off; off >>= 1) {
        s0 += __shfl_xor(s0, off, 64);
        s1 += __shfl_xor(s1, off, 64);
    }
    if (lane == 0) { reds[0][wave] = s0; reds[1][wave] = s1; }
    __syncthreads();
    float bs0 = reds[0][0], bs1 = reds[1][0];
    #pragma unroll
    for (int w = 1; w < 8; ++w) { bs0 += reds[0][w]; bs1 += reds[1][w]; }
    const float e0 = ex0 * __builtin_amdgcn_rcpf(bs0);
    const float e1 = ex1 * __builtin_amdgcn_rcpf(bs1);
    e_out[bt0 * TEn + tid]       = e0;
    e_out[(bt0 + 1) * TEn + tid] = e1;
    sc0[tid] = e0;               // all reads of old sc done before last sync
    sc1[tid] = e1;
    __syncthreads();

    // ---- context for both t: c[bt0+t, h] = sum_s e_t[s] * enc[b, s, h]
    // thread = (hl = tid&31 -> h = 4*hl..) x (sp = tid>>5, 32 s each)
    {
        const int hl = tid & 31;
        const int sp = tid >> 5;
        const float* eb = enc + (b * TEn + sp * 32) * HEn + hl * 4;
        const float* p0 = sc0 + sp * 32;
        const float* p1 = sc1 + sp * 32;
        float4 a0 = {0.f, 0.f, 0.f, 0.f};
        float4 a1 = {0.f, 0.f, 0.f, 0.f};
        #pragma unroll 4
        for (int i = 0; i < 32; ++i) {
            const float w0 = p0[i];
            const float w1 = p1[i];
            const float4 ev = *(const float4*)(eb + i * HEn);  // one load, 2 accs
            a0.x = fmaf(w0, ev.x, a0.x);  a1.x = fmaf(w1, ev.x, a1.x);
            a0.y = fmaf(w0, ev.y, a0.y);  a1.y = fmaf(w1, ev.y, a1.y);
            a0.z = fmaf(w0, ev.z, a0.z);  a1.z = fmaf(w1, ev.z, a1.z);
            a0.w = fmaf(w0, ev.w, a0.w);  a1.w = fmaf(w1, ev.w, a1.w);
        }
        *(float4*)&part[sp][hl * 4]      = a0;
        *(float4*)&part[16 + sp][hl * 4] = a1;
    }
    __syncthreads();
    if (tid < 2 * HEn) {
        const int tsel = tid >> 7;        // 0 or 1
        const int h    = tid & 127;
        float s = 0.f;
        #pragma unroll
        for (int p = 0; p < 16; ++p) s += part[tsel * 16 + p][h];
        c_out[(bt0 + tsel) * HEn + h] = s;
    }
}

extern "C" void kernel_launch(void* const* d_in, const int* in_sizes, int n_in,
                              void* d_out, int out_size, void* d_ws, size_t ws_size,
                              hipStream_t stream) {
    const float* enc = (const float*)d_in[0];   // [B,TE,HE]
    const float* dec = (const float*)d_in[1];   // [B,TD,HD]
    const float* W   = (const float*)d_in[2];   // [HE,HE]
    const float* U   = (const float*)d_in[3];   // [HD,HE]
    const float* V   = (const float*)d_in[4];   // [HE,1]
    float* out   = (float*)d_out;
    float* c_out = out;                         // [B,TD,HE]
    float* e_out = out + Bn * TDn * HEn;        // [B,TD,TE]
    float* Ws    = (float*)d_ws;                // [B,TE,HE] scratch, 1 MB

    ws_gemm_kernel<<<(Bn * TEn) / 4, 512, 0, stream>>>(enc, W, Ws);
    attn_kernel<<<(Bn * TDn) / 2, 512, 0, stream>>>(enc, dec, U, V, Ws, c_out, e_out);
}

// Round 4
// 94.784 us; speedup vs baseline: 1.3749x; 1.0127x over previous
//
#include <hip/hip_runtime.h>

#define Bn  4
#define TEn 512
#define TDn 256
#define HEn 128
#define HDn 256

__device__ __forceinline__ float tanh_fast(float x) {
    // tanh(x) = 1 - 2/(exp(2x)+1); exact at +/-inf (rcp(inf)=0, exp(-inf)=0)
    float e = __expf(2.0f * x);
    return 1.0f - 2.0f * __builtin_amdgcn_rcpf(e + 1.0f);
}

// Ws[r, c] = sum_k enc[r, k] * W[k, c]; 4 rows per block, enc rows staged in LDS.
__global__ __launch_bounds__(512) void ws_gemm_kernel(
    const float* __restrict__ enc, const float* __restrict__ W,
    float* __restrict__ Ws)
{
    __shared__ __align__(16) float enc_lds[4 * HEn];
    const int tid = threadIdx.x;
    const int c   = tid & (HEn - 1);
    const int rl  = tid >> 7;              // wave-uniform
    const int r0  = blockIdx.x * 4;
    enc_lds[tid] = enc[r0 * HEn + tid];    // coalesced 2 KB stage
    __syncthreads();
    const float* wc = W + c;               // coalesced across lanes
    const float* er = enc_lds + rl * HEn;  // LDS broadcast
    float acc = 0.f;
    #pragma unroll 4
    for (int k = 0; k < HEn; k += 8) {
        float4 e0 = *(const float4*)(er + k);
        float4 e1 = *(const float4*)(er + k + 4);
        acc = fmaf(e0.x, wc[(k + 0) * HEn], acc);
        acc = fmaf(e0.y, wc[(k + 1) * HEn], acc);
        acc = fmaf(e0.z, wc[(k + 2) * HEn], acc);
        acc = fmaf(e0.w, wc[(k + 3) * HEn], acc);
        acc = fmaf(e1.x, wc[(k + 4) * HEn], acc);
        acc = fmaf(e1.y, wc[(k + 5) * HEn], acc);
        acc = fmaf(e1.z, wc[(k + 6) * HEn], acc);
        acc = fmaf(e1.w, wc[(k + 7) * HEn], acc);
    }
    Ws[(r0 + rl) * HEn + c] = acc;
}

// One block per (b, 4 decoder steps): grid = 256 = 1 block/CU, 16 waves/CU.
// Every Ws/enc float4 load feeds 4 independent chains.
__global__ __launch_bounds__(1024, 4) void attn_kernel(
    const float* __restrict__ enc, const float* __restrict__ dec,
    const float* __restrict__ U, const float* __restrict__ V,
    const float* __restrict__ Ws, float* __restrict__ c_out,
    float* __restrict__ e_out)
{
    const int b    = blockIdx.x >> 6;
    const int t0   = (blockIdx.x & 63) * 4;
    const int bt0  = b * TDn + t0;      // rows bt0 .. bt0+3
    const int tid  = threadIdx.x;
    const int lane = tid & 63;
    const int wave = tid >> 6;          // 0..15

    __shared__ __align__(16) float dec_lds[4 * HDn];     // 4 KB
    __shared__ __align__(16) float uh[4][HEn];           // 2 KB
    __shared__ __align__(16) float sc[4][TEn];           // 8 KB
    __shared__ __align__(16) float part[32][512];        // 64 KB (Uh + ctx partials)
    __shared__ float redm[4][8];
    __shared__ float reds[4][8];

    // ---- stage all 4 decoder rows (contiguous, coalesced 4 KB)
    dec_lds[tid] = dec[bt0 * HDn + tid];
    __syncthreads();

    // ---- Uh[r][f] = sum_k dec[bt0+r, k] * U[k, f]   (8 k-partitions x 128 f)
    {
        const int f = tid & 127;
        const int p = tid >> 7;                        // 0..7, wave-uniform
        const float* u = U + (p * 32) * HEn + f;       // coalesced
        float a0 = 0.f, a1 = 0.f, a2 = 0.f, a3 = 0.f;
        #pragma unroll 8
        for (int k = 0; k < 32; ++k) {
            const float uk = u[k * HEn];               // loaded once, 4 uses
            const int kk = p * 32 + k;
            a0 = fmaf(dec_lds[kk],            uk, a0);
            a1 = fmaf(dec_lds[HDn + kk],      uk, a1);
            a2 = fmaf(dec_lds[2 * HDn + kk],  uk, a2);
            a3 = fmaf(dec_lds[3 * HDn + kk],  uk, a3);
        }
        part[p][f]       = a0;
        part[p][128 + f] = a1;
        part[p][256 + f] = a2;
        part[p][384 + f] = a3;
    }
    __syncthreads();
    if (tid < 512) {
        const int r = tid >> 7, f = tid & 127;
        float s = 0.f;
        #pragma unroll
        for (int p = 0; p < 8; ++p) s += part[p][r * 128 + f];
        uh[r][f] = s;
    }
    __syncthreads();

    // ---- scores, 4 rows: lane = (s_sub = lane&7) x (f_grp = lane>>3, 16 f)
    {
        const int s_sub = lane & 7;
        const int f0    = (lane >> 3) * 16;
        float4 vv[4], uu[4][4];
        #pragma unroll
        for (int j = 0; j < 4; ++j) {
            vv[j] = *(const float4*)(V + f0 + 4 * j);
            #pragma unroll
            for (int r = 0; r < 4; ++r)
                uu[r][j] = *(const float4*)(&uh[r][f0 + 4 * j]);
        }
        const float* wsb = Ws + (b * TEn + wave * 32) * HEn;
        #pragma unroll
        for (int ci = 0; ci < 4; ++ci) {
            const float* wp = wsb + (ci * 8 + s_sub) * HEn + f0;
            float x0 = 0.f, x1 = 0.f, x2 = 0.f, x3 = 0.f;
            #pragma unroll
            for (int j = 0; j < 4; ++j) {
                float4 w = ((const float4*)wp)[j];     // one load, four chains
                x0 = fmaf(vv[j].x, tanh_fast(w.x + uu[0][j].x), x0);
                x1 = fmaf(vv[j].x, tanh_fast(w.x + uu[1][j].x), x1);
                x2 = fmaf(vv[j].x, tanh_fast(w.x + uu[2][j].x), x2);
                x3 = fmaf(vv[j].x, tanh_fast(w.x + uu[3][j].x), x3);
                x0 = fmaf(vv[j].y, tanh_fast(w.y + uu[0][j].y), x0);
                x1 = fmaf(vv[j].y, tanh_fast(w.y + uu[1][j].y), x1);
                x2 = fmaf(vv[j].y, tanh_fast(w.y + uu[2][j].y), x2);
                x3 = fmaf(vv[j].y, tanh_fast(w.y + uu[3][j].y), x3);
                x0 = fmaf(vv[j].z, tanh_fast(w.z + uu[0][j].z), x0);
                x1 = fmaf(vv[j].z, tanh_fast(w.z + uu[1][j].z), x1);
                x2 = fmaf(vv[j].z, tanh_fast(w.z + uu[2][j].z), x2);
                x3 = fmaf(vv[j].z, tanh_fast(w.z + uu[3][j].z), x3);
                x0 = fmaf(vv[j].w, tanh_fast(w.w + uu[0][j].w), x0);
                x1 = fmaf(vv[j].w, tanh_fast(w.w + uu[1][j].w), x1);
                x2 = fmaf(vv[j].w, tanh_fast(w.w + uu[2][j].w), x2);
                x3 = fmaf(vv[j].w, tanh_fast(w.w + uu[3][j].w), x3);
            }
            x0 += __shfl_xor(x0, 8, 64);  x1 += __shfl_xor(x1, 8, 64);
            x2 += __shfl_xor(x2, 8, 64);  x3 += __shfl_xor(x3, 8, 64);
            x0 += __shfl_xor(x0, 16, 64); x1 += __shfl_xor(x1, 16, 64);
            x2 += __shfl_xor(x2, 16, 64); x3 += __shfl_xor(x3, 16, 64);
            x0 += __shfl_xor(x0, 32, 64); x1 += __shfl_xor(x1, 32, 64);
            x2 += __shfl_xor(x2, 32, 64); x3 += __shfl_xor(x3, 32, 64);
            if (lane < 8) {
                const int s = wave * 32 + ci * 8 + lane;
                sc[0][s] = x0; sc[1][s] = x1; sc[2][s] = x2; sc[3][s] = x3;
            }
        }
    }
    __syncthreads();

    // ---- softmax: thread owns s = tid&511 for row pair r0 = (tid>>9)*2
    {
        const int s  = tid & 511;
        const int r0 = (tid >> 9) * 2;
        const int w8 = wave & 7;
        const float v0 = sc[r0][s];
        const float v1 = sc[r0 + 1][s];
        float m0 = v0, m1 = v1;
        #pragma unroll
        for (int off = 32; off; off >>= 1) {
            m0 = fmaxf(m0, __shfl_xor(m0, off, 64));
            m1 = fmaxf(m1, __shfl_xor(m1, off, 64));
        }
        if (lane == 0) { redm[r0][w8] = m0; redm[r0 + 1][w8] = m1; }
        __syncthreads();
        float bm0 = redm[r0][0], bm1 = redm[r0 + 1][0];
        #pragma unroll
        for (int w = 1; w < 8; ++w) {
            bm0 = fmaxf(bm0, redm[r0][w]);
            bm1 = fmaxf(bm1, redm[r0 + 1][w]);
        }
        const float ex0 = __expf(v0 - bm0);
        const float ex1 = __expf(v1 - bm1);
        float s0 = ex0, s1 = ex1;
        #pragma unroll
        for (int off = 32; off; off >>= 1) {
            s0 += __shfl_xor(s0, off, 64);
            s1 += __shfl_xor(s1, off, 64);
        }
        if (lane == 0) { reds[r0][w8] = s0; reds[r0 + 1][w8] = s1; }
        __syncthreads();
        float bs0 = reds[r0][0], bs1 = reds[r0 + 1][0];
        #pragma unroll
        for (int w = 1; w < 8; ++w) { bs0 += reds[r0][w]; bs1 += reds[r0 + 1][w]; }
        const float e0 = ex0 * __builtin_amdgcn_rcpf(bs0);
        const float e1 = ex1 * __builtin_amdgcn_rcpf(bs1);
        e_out[(bt0 + r0) * TEn + s]     = e0;
        e_out[(bt0 + r0 + 1) * TEn + s] = e1;
        sc[r0][s]     = e0;      // same thread read this slot; no race
        sc[r0 + 1][s] = e1;
    }
    __syncthreads();

    // ---- context: c[bt0+r, h] = sum_s e_r[s] * enc[b, s, h]
    // thread = (hl = tid&31 -> h = 4*hl..) x (sp = tid>>5, 16 s each)
    {
        const int hl = tid & 31;
        const int sp = tid >> 5;                       // 0..31
        const float* eb = enc + (b * TEn + sp * 16) * HEn + hl * 4;
        float4 a0 = {0,0,0,0}, a1 = {0,0,0,0}, a2 = {0,0,0,0}, a3 = {0,0,0,0};
        #pragma unroll 4
        for (int i = 0; i < 16; ++i) {
            const int s = sp * 16 + i;
            const float4 ev = *(const float4*)(eb + i * HEn);  // one load, 4 accs
            const float w0 = sc[0][s], w1 = sc[1][s];
            const float w2 = sc[2][s], w3 = sc[3][s];
            a0.x = fmaf(w0, ev.x, a0.x); a1.x = fmaf(w1, ev.x, a1.x);
            a2.x = fmaf(w2, ev.x, a2.x); a3.x = fmaf(w3, ev.x, a3.x);
            a0.y = fmaf(w0, ev.y, a0.y); a1.y = fmaf(w1, ev.y, a1.y);
            a2.y = fmaf(w2, ev.y, a2.y); a3.y = fmaf(w3, ev.y, a3.y);
            a0.z = fmaf(w0, ev.z, a0.z); a1.z = fmaf(w1, ev.z, a1.z);
            a2.z = fmaf(w2, ev.z, a2.z); a3.z = fmaf(w3, ev.z, a3.z);
            a0.w = fmaf(w0, ev.w, a0.w); a1.w = fmaf(w1, ev.w, a1.w);
            a2.w = fmaf(w2, ev.w, a2.w); a3.w = fmaf(w3, ev.w, a3.w);
        }
        *(float4*)&part[sp][0   + hl * 4] = a0;
        *(float4*)&part[sp][128 + hl * 4] = a1;
        *(float4*)&part[sp][256 + hl * 4] = a2;
        *(float4*)&part[sp][384 + hl * 4] = a3;
    }
    __syncthreads();
    if (tid < 512) {
        const int r = tid >> 7, h = tid & 127;
        float s = 0.f;
        #pragma unroll
        for (int p = 0; p < 32; ++p) s += part[p][r * 128 + h];
        c_out[(bt0 + r) * HEn + h] = s;
    }
}

extern "C" void kernel_launch(void* const* d_in, const int* in_sizes, int n_in,
                              void* d_out, int out_size, void* d_ws, size_t ws_size,
                              hipStream_t stream) {
    const float* enc = (const float*)d_in[0];   // [B,TE,HE]
    const float* dec = (const float*)d_in[1];   // [B,TD,HD]
    const float* W   = (const float*)d_in[2];   // [HE,HE]
    const float* U   = (const float*)d_in[3];   // [HD,HE]
    const float* V   = (const float*)d_in[4];   // [HE,1]
    float* out   = (float*)d_out;
    float* c_out = out;                         // [B,TD,HE]
    float* e_out = out + Bn * TDn * HEn;        // [B,TD,TE]
    float* Ws    = (float*)d_ws;                // [B,TE,HE] scratch, 1 MB

    ws_gemm_kernel<<<(Bn * TEn) / 4, 512, 0, stream>>>(enc, W, Ws);
    attn_kernel<<<(Bn * TDn) / 4, 1024, 0, stream>>>(enc, dec, U, V, Ws, c_out, e_out);
}